// Round 12
// baseline (137.974 us; speedup 1.0000x reference)
//
#include <hip/hip_runtime.h>

#define NN 8192
#define FI 256
#define FO 128
#define GAT_ALPHA 0.2f

typedef _Float16 f16x8 __attribute__((ext_vector_type(8)));
typedef _Float16 f16x2 __attribute__((ext_vector_type(2)));
typedef float f32x4 __attribute__((ext_vector_type(4)));
typedef unsigned char uchar;
typedef unsigned short ushort16;
typedef unsigned int uint32;

// ---------------------------------------------------------------------------
// K1: Wh[j][f] = sum_k h[j][k] * W[f][k] + b[f]  (fp32, LDS-tiled, all-b128)
//   + fused k1b: s1/s2 scores + exp tables via 32-lane shfl reduction.
// ---------------------------------------------------------------------------
__global__ __launch_bounds__(256) void k1_wh(const float* __restrict__ h,
                                             const float* __restrict__ W,
                                             const float* __restrict__ bias,
                                             const float* __restrict__ a,
                                             float* __restrict__ Wh,
                                             float4* __restrict__ r4,
                                             float4* __restrict__ c4,
                                             float2* __restrict__ r2,
                                             _Float16* __restrict__ ey16,
                                             _Float16* __restrict__ ez16,
                                             float* __restrict__ s2x,
                                             float* __restrict__ corr) {
  __shared__ __align__(16) float hs[32][260];  // 260: 16B-aligned rows
  __shared__ __align__(16) float wt[32][FO];
  const int t = threadIdx.x;
  const int j0 = blockIdx.x * 32;
  if (blockIdx.x == 0 && t < FO) corr[t] = 0.f;
  {
    const int row = t >> 3, c0 = (t & 7) * 32;
    const float* src = h + (size_t)(j0 + row) * FI + c0;
#pragma unroll
    for (int e = 0; e < 8; ++e) {
      float4 v = *(const float4*)(src + 4 * e);
      hs[row][c0 + 4 * e + 0] = v.x;
      hs[row][c0 + 4 * e + 1] = v.y;
      hs[row][c0 + 4 * e + 2] = v.z;
      hs[row][c0 + 4 * e + 3] = v.w;
    }
  }
  const int f4 = (t & 31) * 4;
  const int r0 = (t >> 5) * 4;
  float acc[4][4];
#pragma unroll
  for (int r = 0; r < 4; ++r)
#pragma unroll
    for (int e = 0; e < 4; ++e) acc[r][e] = 0.f;

  for (int kc = 0; kc < FI; kc += 32) {
    __syncthreads();
    {
      const int f = t >> 1, kb = (t & 1) * 16;
      const float* wsrc = W + (size_t)f * FI + kc + kb;
#pragma unroll
      for (int e = 0; e < 16; ++e) wt[kb + e][f] = wsrc[e];
    }
    __syncthreads();
#pragma unroll
    for (int k = 0; k < 32; k += 4) {
      float4 wv[4], hv[4];
#pragma unroll
      for (int i = 0; i < 4; ++i) wv[i] = *(const float4*)&wt[k + i][f4];
#pragma unroll
      for (int r = 0; r < 4; ++r) hv[r] = *(const float4*)&hs[r0 + r][kc + k];
#pragma unroll
      for (int r = 0; r < 4; ++r) {
        acc[r][0] += hv[r].x * wv[0].x + hv[r].y * wv[1].x + hv[r].z * wv[2].x + hv[r].w * wv[3].x;
        acc[r][1] += hv[r].x * wv[0].y + hv[r].y * wv[1].y + hv[r].z * wv[2].y + hv[r].w * wv[3].y;
        acc[r][2] += hv[r].x * wv[0].z + hv[r].y * wv[1].z + hv[r].z * wv[2].z + hv[r].w * wv[3].z;
        acc[r][3] += hv[r].x * wv[0].w + hv[r].y * wv[1].w + hv[r].z * wv[2].w + hv[r].w * wv[3].w;
      }
    }
  }
  const float4 bv = *(const float4*)&bias[f4];
  const float4 a1v = *(const float4*)&a[f4];
  const float4 a2v = *(const float4*)&a[FO + f4];
  float s1p[4], s2p[4];
#pragma unroll
  for (int r = 0; r < 4; ++r) {
    float4 o;
    o.x = acc[r][0] + bv.x;
    o.y = acc[r][1] + bv.y;
    o.z = acc[r][2] + bv.z;
    o.w = acc[r][3] + bv.w;
    *(float4*)&Wh[(size_t)(j0 + r0 + r) * FO + f4] = o;
    s1p[r] = o.x * a1v.x + o.y * a1v.y + o.z * a1v.z + o.w * a1v.w;
    s2p[r] = o.x * a2v.x + o.y * a2v.y + o.z * a2v.z + o.w * a2v.w;
  }
#pragma unroll
  for (int m = 16; m >= 1; m >>= 1) {
#pragma unroll
    for (int r = 0; r < 4; ++r) {
      s1p[r] += __shfl_xor(s1p[r], m);
      s2p[r] += __shfl_xor(s2p[r], m);
    }
  }
  if ((t & 31) == 0) {
#pragma unroll
    for (int r = 0; r < 4; ++r) {
      const int j = j0 + r0 + r;
      const float s1 = s1p[r], s2 = s2p[r];
      const float e1 = expf(s1), e1a = expf(GAT_ALPHA * s1);
      const float e2 = expf(s2), e2a = expf(GAT_ALPHA * s2);
      float4 rv; rv.x = s1; rv.y = e1; rv.z = e1a; rv.w = 0.f;
      float4 cv; cv.x = s2; cv.y = e2; cv.z = e2a; cv.w = 0.f;
      r4[j] = rv;
      c4[j] = cv;
      r2[j] = make_float2(e1, e1a);
      ey16[j] = (_Float16)e2;
      ez16[j] = (_Float16)e2a;
      s2x[j] = s2;
    }
  }
}

// ---------------------------------------------------------------------------
// K2: single pass over adj (268 MB HBM floor). Thread owns 8 consecutive j
// (2x int4 = 32 B/lane), packs 8 activity bits into one byte, coalesced
// byte stores; 8 accP/accN register accumulators.
// ---------------------------------------------------------------------------
__global__ __launch_bounds__(256) void k2_stats(const int* __restrict__ adj,
                                                const float4* __restrict__ r4,
                                                const float* __restrict__ s2x,
                                                uchar* __restrict__ bitsB,
                                                float2* __restrict__ zpart) {
  __shared__ float4 rs[64];
  const int t = threadIdx.x;
  const int jc = blockIdx.x & 3;
  const int ic = blockIdx.x >> 2;
  const int i0 = ic * 64;
  const int j0 = jc * 2048 + t * 8;
  if (t < 64) rs[t] = r4[i0 + t];
  const float4 ca = *(const float4*)(s2x + j0);
  const float4 cb = *(const float4*)(s2x + j0 + 4);
  const float cx[8] = {ca.x, ca.y, ca.z, ca.w, cb.x, cb.y, cb.z, cb.w};
  float accP[8], accN[8];
#pragma unroll
  for (int e = 0; e < 8; ++e) { accP[e] = 0.f; accN[e] = 0.f; }
  __syncthreads();
  const int4* ap = (const int4*)(adj + (size_t)i0 * NN + j0);
  uchar* bp = bitsB + (size_t)i0 * (NN / 8) + jc * 256 + t;
  for (int ir = 0; ir < 64; ir += 8) {
    int4 av[8][2];
#pragma unroll
    for (int u = 0; u < 8; ++u) {
      av[u][0] = ap[(size_t)(ir + u) * (NN / 4)];
      av[u][1] = ap[(size_t)(ir + u) * (NN / 4) + 1];
    }
#pragma unroll
    for (int u = 0; u < 8; ++u) {
      const float4 ri = rs[ir + u];
      const int aa[8] = {av[u][0].x, av[u][0].y, av[u][0].z, av[u][0].w,
                         av[u][1].x, av[u][1].y, av[u][1].z, av[u][1].w};
      uint32 byte = 0;
#pragma unroll
      for (int e = 0; e < 8; ++e) {
        const bool act = aa[e] > 0;
        byte |= act ? (1u << e) : 0u;
        const bool pos = (ri.x + cx[e]) >= 0.f;
        accP[e] += (act && pos) ? ri.y : 0.f;
        accN[e] += (act && !pos) ? ri.z : 0.f;
      }
      bp[(size_t)(ir + u) * (NN / 8)] = (uchar)byte;
    }
  }
  float2* zp = zpart + (size_t)ic * NN + j0;
#pragma unroll
  for (int e = 0; e < 8; ++e) zp[e] = make_float2(accP[e], accN[e]);
}

// ---------------------------------------------------------------------------
// K3: Z_j from 128 partials; emit Wfrag in MFMA-B-fragment-major layout.
// Empty cols -> corr[f] (uniform softmax fix).
// ---------------------------------------------------------------------------
__global__ __launch_bounds__(256) void k3_scale(const float* __restrict__ Wh,
                                                const float4* __restrict__ c4,
                                                const float2* __restrict__ zpart,
                                                _Float16* __restrict__ Wfrag,
                                                float* __restrict__ corr) {
  __shared__ float rz[64];
  __shared__ int emp[64];
  __shared__ float2 psum[256];
  __shared__ __align__(16) _Float16 tile[FO * 64];
  const int t = threadIdx.x;
  const int j0 = blockIdx.x * 64;
  {
    const int jl = t & 63, q = t >> 6;
    float p = 0.f, n = 0.f;
    for (int ic = q * 32; ic < q * 32 + 32; ++ic) {
      const float2 z = zpart[(size_t)ic * NN + j0 + jl];
      p += z.x;
      n += z.y;
    }
    psum[t] = make_float2(p, n);
  }
  __syncthreads();
  if (t < 64) {
    const float p = psum[t].x + psum[64 + t].x + psum[128 + t].x + psum[192 + t].x;
    const float n = psum[t].y + psum[64 + t].y + psum[128 + t].y + psum[192 + t].y;
    const float4 cj = c4[j0 + t];
    const float Z = cj.y * p + cj.z * n;
    rz[t] = (Z > 0.f) ? 1.f / Z : 0.f;
    emp[t] = (Z > 0.f) ? 0 : 1;
  }
  __syncthreads();
  const int f = t & 127, half = t >> 7;
  const unsigned swf = (unsigned)((f & 7) << 4);
  for (int r = half; r < 64; r += 2) {
    const float v = Wh[(size_t)(j0 + r) * FO + f];
    *(_Float16*)((char*)tile + f * 128 + (((unsigned)(r * 2)) ^ swf)) =
        (_Float16)(v * rz[r]);
    if (emp[r]) atomicAdd(&corr[f], v * (1.f / 8192.f));
  }
  __syncthreads();
#pragma unroll
  for (int q = 0; q < 4; ++q) {
    const int G = t + 256 * q;
    const int kcfb = G >> 6, gl = G & 63;
    const int kc = kcfb >> 3, fb = kcfb & 7;
    const int gf = fb * 16 + (gl & 15);
    const int jloc = kc * 32 + (gl >> 4) * 8;
    const f16x8 v = *(const f16x8*)((const char*)tile + gf * 128 +
                                    (((unsigned)(jloc * 2)) ^ ((unsigned)((gf & 7) << 4))));
    ((f16x8*)Wfrag)[(size_t)(((j0 >> 5) + kc) * 8 + fb) * 64 + gl] = v;
  }
}

// ---------------------------------------------------------------------------
// K4: partial h' = P~ @ (Wh/Z) over this block's K-range -> part[kq].
//   P~pair = pk_max(pk_mul(rx2, ey), pk_mul(ry2, ez)) & maskLUT[bits]
// BM=32, 256 thr = 4 waves (1x4), ksplit=4. PHASE = 128 k (16 phases of
// 4 kchunks) -> HALF the barriers of the 64-k version. P dbuf 16 KB.
// mb/ey/ez dbuf'd 2 phases ahead; B (8 frags) single-buffered per phase
// (issued at phase start, consumed at end, covered by 4 blocks/CU).
// Barriers drain lgkmcnt only; setprio on MFMA.
// ---------------------------------------------------------------------------
#define BARRIER_LDS()                                          \
  do {                                                         \
    __builtin_amdgcn_sched_barrier(0);                         \
    asm volatile("s_waitcnt lgkmcnt(0)" ::: "memory");         \
    __builtin_amdgcn_s_barrier();                              \
    __builtin_amdgcn_sched_barrier(0);                         \
  } while (0)

__global__ __launch_bounds__(256, 4) void k4_main(const uchar* __restrict__ bitsB,
                                                  const float2* __restrict__ r2,
                                                  const _Float16* __restrict__ ey16,
                                                  const _Float16* __restrict__ ez16,
                                                  const _Float16* __restrict__ Wfrag,
                                                  float* __restrict__ part) {
  __shared__ __align__(16) _Float16 P[2][32 * 128];  // 16 KB
  __shared__ uint32 lut[256][4];                     // 4 KB: byte -> 4 mask32
  const int t = threadIdx.x;
  const int rowtile = blockIdx.x >> 2;
  const int kq = blockIdx.x & 3;
  const int rowbase = rowtile * 32;
  const int koff = kq * 2048;

  {
#pragma unroll
    for (int p = 0; p < 4; ++p) {
      const uint32 lo = ((t >> (2 * p)) & 1) ? 0x0000FFFFu : 0u;
      const uint32 hi = ((t >> (2 * p + 1)) & 1) ? 0xFFFF0000u : 0u;
      lut[t][p] = lo | hi;
    }
  }

  // ---- P-gen ids: row pr (0..31), 16 consecutive k at jq*16 per phase
  const int pr = t >> 3, jq = t & 7;
  const float2 rr = r2[rowbase + pr];
  const f16x2 rx2 = {(_Float16)rr.x, (_Float16)rr.x};
  const f16x2 ry2 = {(_Float16)rr.y, (_Float16)rr.y};
  const uchar* bp = bitsB + (size_t)(rowbase + pr) * (NN / 8) + (koff >> 3) + jq * 2;
  const _Float16* eyp = ey16 + koff + jq * 16;
  const _Float16* ezp = ez16 + koff + jq * 16;
  const unsigned psw = (unsigned)((pr & 7) << 4);
  char* const prow0 = (char*)&P[0][0] + pr * 256;
  char* const prow1 = (char*)&P[1][0] + pr * 256;
  const unsigned off0 = ((unsigned)(jq * 32)) ^ psw;
  const unsigned off1 = ((unsigned)(jq * 32 + 16)) ^ psw;

  // ---- MFMA ids: wave = col-tile (4 waves cover 128 cols)
  const int lane = t & 63, wc = t >> 6;
  const int kgrp = lane >> 4, l15 = lane & 15;
  const unsigned asw = (unsigned)((l15 & 7) << 4);
  const int ar0 = l15 * 256;          // rows 0-15 (256 B/row)
  const int ar1 = ar0 + 16 * 256;     // rows 16-31

  f32x4 acc00 = {0.f, 0.f, 0.f, 0.f}, acc01 = {0.f, 0.f, 0.f, 0.f};
  f32x4 acc10 = {0.f, 0.f, 0.f, 0.f}, acc11 = {0.f, 0.f, 0.f, 0.f};

  ushort16 mb0, mb1;
  uint4 eya0, eyb0, eza0, ezb0, eya1, eyb1, eza1, ezb1;
  f16x8 B00, B01, B10, B11, B20, B21, B30, B31;

#define LOADSMALL(PH, MB, EYA, EYB, EZA, EZB)          \
  do {                                                 \
    MB = *(const ushort16*)(bp + (PH)*16);             \
    EYA = *(const uint4*)(eyp + (PH)*128);             \
    EYB = *(const uint4*)(eyp + (PH)*128 + 8);         \
    EZA = *(const uint4*)(ezp + (PH)*128);             \
    EZB = *(const uint4*)(ezp + (PH)*128 + 8);         \
  } while (0)

#define LOADB(PH)                                                                   \
  do {                                                                              \
    const _Float16* _b = Wfrag + ((size_t)((kq * 64 + (PH)*4) * 8 + wc * 2) * 64 + lane) * 8; \
    B00 = *(const f16x8*)(_b);                                                      \
    B01 = *(const f16x8*)(_b + 512);                                                \
    B10 = *(const f16x8*)(_b + 4096);                                               \
    B11 = *(const f16x8*)(_b + 4096 + 512);                                         \
    B20 = *(const f16x8*)(_b + 8192);                                               \
    B21 = *(const f16x8*)(_b + 8192 + 512);                                         \
    B30 = *(const f16x8*)(_b + 12288);                                              \
    B31 = *(const f16x8*)(_b + 12288 + 512);                                        \
  } while (0)

#define PKHALF(OUT, EY, EZ, MSK)                                                     \
  do {                                                                               \
    const uint32 _eys[4] = {EY.x, EY.y, EY.z, EY.w};                                 \
    const uint32 _ezs[4] = {EZ.x, EZ.y, EZ.z, EZ.w};                                 \
    const uint32 _ms[4] = {MSK.x, MSK.y, MSK.z, MSK.w};                              \
    uint32 _o[4];                                                                    \
    _Pragma("unroll") for (int _p = 0; _p < 4; ++_p) {                               \
      const f16x2 _a = __builtin_bit_cast(f16x2, _eys[_p]) * rx2;                    \
      const f16x2 _b2 = __builtin_bit_cast(f16x2, _ezs[_p]) * ry2;                   \
      const f16x2 _mx = __builtin_elementwise_max(_a, _b2);                          \
      _o[_p] = __builtin_bit_cast(uint32, _mx) & _ms[_p];                            \
    }                                                                                \
    OUT.x = _o[0]; OUT.y = _o[1]; OUT.z = _o[2]; OUT.w = _o[3];                      \
  } while (0)

#define PGEN(PROW, MB, EYA, EYB, EZA, EZB)                                           \
  do {                                                                               \
    const uint32 _b0 = (MB) & 0xFF, _b1 = ((MB) >> 8) & 0xFF;                        \
    const uint4 _m0 = *(const uint4*)(&lut[_b0][0]);                                 \
    const uint4 _m1 = *(const uint4*)(&lut[_b1][0]);                                 \
    uint4 _v0, _v1;                                                                  \
    PKHALF(_v0, EYA, EZA, _m0);                                                      \
    PKHALF(_v1, EYB, EZB, _m1);                                                      \
    *(uint4*)(PROW + off0) = _v0;                                                    \
    *(uint4*)(PROW + off1) = _v1;                                                    \
  } while (0)

#define DO_MFMA(BUF)                                                                 \
  do {                                                                               \
    const char* _Pb = (const char*)&P[BUF][0];                                       \
    const f16x8 a00 = *(const f16x8*)(_Pb + ar0 + ((((unsigned)(kgrp * 16))) ^ asw));         \
    const f16x8 a01 = *(const f16x8*)(_Pb + ar0 + (((unsigned)(64 + kgrp * 16)) ^ asw));      \
    const f16x8 a02 = *(const f16x8*)(_Pb + ar0 + (((unsigned)(128 + kgrp * 16)) ^ asw));     \
    const f16x8 a03 = *(const f16x8*)(_Pb + ar0 + (((unsigned)(192 + kgrp * 16)) ^ asw));     \
    const f16x8 a10 = *(const f16x8*)(_Pb + ar1 + ((((unsigned)(kgrp * 16))) ^ asw));         \
    const f16x8 a11 = *(const f16x8*)(_Pb + ar1 + (((unsigned)(64 + kgrp * 16)) ^ asw));      \
    const f16x8 a12 = *(const f16x8*)(_Pb + ar1 + (((unsigned)(128 + kgrp * 16)) ^ asw));     \
    const f16x8 a13 = *(const f16x8*)(_Pb + ar1 + (((unsigned)(192 + kgrp * 16)) ^ asw));     \
    __builtin_amdgcn_s_setprio(1);                                                   \
    acc00 = __builtin_amdgcn_mfma_f32_16x16x32_f16(a00, B00, acc00, 0, 0, 0);        \
    acc01 = __builtin_amdgcn_mfma_f32_16x16x32_f16(a00, B01, acc01, 0, 0, 0);        \
    acc10 = __builtin_amdgcn_mfma_f32_16x16x32_f16(a10, B00, acc10, 0, 0, 0);        \
    acc11 = __builtin_amdgcn_mfma_f32_16x16x32_f16(a10, B01, acc11, 0, 0, 0);        \
    acc00 = __builtin_amdgcn_mfma_f32_16x16x32_f16(a01, B10, acc00, 0, 0, 0);        \
    acc01 = __builtin_amdgcn_mfma_f32_16x16x32_f16(a01, B11, acc01, 0, 0, 0);        \
    acc10 = __builtin_amdgcn_mfma_f32_16x16x32_f16(a11, B10, acc10, 0, 0, 0);        \
    acc11 = __builtin_amdgcn_mfma_f32_16x16x32_f16(a11, B11, acc11, 0, 0, 0);        \
    acc00 = __builtin_amdgcn_mfma_f32_16x16x32_f16(a02, B20, acc00, 0, 0, 0);        \
    acc01 = __builtin_amdgcn_mfma_f32_16x16x32_f16(a02, B21, acc01, 0, 0, 0);        \
    acc10 = __builtin_amdgcn_mfma_f32_16x16x32_f16(a12, B20, acc10, 0, 0, 0);        \
    acc11 = __builtin_amdgcn_mfma_f32_16x16x32_f16(a12, B21, acc11, 0, 0, 0);        \
    acc00 = __builtin_amdgcn_mfma_f32_16x16x32_f16(a03, B30, acc00, 0, 0, 0);        \
    acc01 = __builtin_amdgcn_mfma_f32_16x16x32_f16(a03, B31, acc01, 0, 0, 0);        \
    acc10 = __builtin_amdgcn_mfma_f32_16x16x32_f16(a13, B30, acc10, 0, 0, 0);        \
    acc11 = __builtin_amdgcn_mfma_f32_16x16x32_f16(a13, B31, acc11, 0, 0, 0);        \
    __builtin_amdgcn_s_setprio(0);                                                   \
  } while (0)

  // ---- prologue (sync covers lut writes before first PGEN lut read)
  LOADSMALL(0, mb0, eya0, eyb0, eza0, ezb0);
  LOADSMALL(1, mb1, eya1, eyb1, eza1, ezb1);
  __syncthreads();
  PGEN(prow0, mb0, eya0, eyb0, eza0, ezb0);  // phase 0
  BARRIER_LDS();

  for (int p = 0; p < 16; p += 2) {
    // ---- even half: compute phase p
    LOADB(p);
    PGEN(prow1, mb1, eya1, eyb1, eza1, ezb1);              // P for phase p+1
    if (p + 2 < 16) LOADSMALL(p + 2, mb0, eya0, eyb0, eza0, ezb0);
    DO_MFMA(0);
    BARRIER_LDS();
    // ---- odd half: compute phase p+1
    LOADB(p + 1);
    if (p + 2 < 16) PGEN(prow0, mb0, eya0, eyb0, eza0, ezb0);  // P for phase p+2
    if (p + 3 < 16) LOADSMALL(p + 3, mb1, eya1, eyb1, eza1, ezb1);
    DO_MFMA(1);
    BARRIER_LDS();
  }

#undef LOADSMALL
#undef LOADB
#undef PKHALF
#undef PGEN
#undef DO_MFMA

  // ---- epilogue: plain stores to this block's private partial buffer
  const int orow = rowbase + kgrp * 4;
  const int ocol = wc * 32 + l15;
  float* aP = part + (size_t)kq * NN * FO + (size_t)orow * FO + ocol;
#pragma unroll
  for (int r = 0; r < 4; ++r) {
    aP[(size_t)r * FO] = acc00[r];
    aP[(size_t)r * FO + 16] = acc01[r];
    aP[(size_t)(16 + r) * FO] = acc10[r];
    aP[(size_t)(16 + r) * FO + 16] = acc11[r];
  }
}

// ---------------------------------------------------------------------------
// K5: out = elu(sum_q part[q] + corr), 4 partials
// ---------------------------------------------------------------------------
__global__ __launch_bounds__(256) void k5_fin(const float* __restrict__ part,
                                              const float* __restrict__ corr,
                                              float* __restrict__ out) {
  const int idx = blockIdx.x * 256 + threadIdx.x;  // float4 index, 262144 total
  const float4 p0 = ((const float4*)part)[idx];
  const float4 p1 = ((const float4*)(part + (size_t)NN * FO))[idx];
  const float4 p2 = ((const float4*)(part + (size_t)2 * NN * FO))[idx];
  const float4 p3 = ((const float4*)(part + (size_t)3 * NN * FO))[idx];
  const float4 c = ((const float4*)corr)[idx & 31];
  float4 v;
  v.x = p0.x + p1.x + p2.x + p3.x + c.x;
  v.y = p0.y + p1.y + p2.y + p3.y + c.y;
  v.z = p0.z + p1.z + p2.z + p3.z + c.z;
  v.w = p0.w + p1.w + p2.w + p3.w + c.w;
  v.x = (v.x > 0.f) ? v.x : (expf(v.x) - 1.f);
  v.y = (v.y > 0.f) ? v.y : (expf(v.y) - 1.f);
  v.z = (v.z > 0.f) ? v.z : (expf(v.z) - 1.f);
  v.w = (v.w > 0.f) ? v.w : (expf(v.w) - 1.f);
  ((float4*)out)[idx] = v;
}

// ---------------------------------------------------------------------------
extern "C" void kernel_launch(void* const* d_in, const int* in_sizes, int n_in,
                              void* d_out, int out_size, void* d_ws, size_t ws_size,
                              hipStream_t stream) {
  const float* h = (const float*)d_in[0];
  const int* adj = (const int*)d_in[1];
  const float* W = (const float*)d_in[2];
  const float* b = (const float*)d_in[3];
  const float* a = (const float*)d_in[4];
  float* out = (float*)d_out;
  char* ws = (char*)d_ws;

  // workspace carve (~40 MB total; d_ws is ~1 GB per harness poison-fill size)
  float* Wh = (float*)(ws + 0);                                   // 4 MB  [k1..k3]
  _Float16* Wfrag = (_Float16*)(ws + 0x400000);                   // 2 MB  [k3..k4]
  uchar* bits = (uchar*)(ws + 0x600000);                          // 8 MB  [k2..k4]
  float2* zpart = (float2*)(ws + 0xE00000);                       // 8 MB  [k2..k3]
  float4* r4 = (float4*)(ws + 0x1600000);                         // 128 KB
  float4* c4 = (float4*)(ws + 0x1620000);                         // 128 KB
  float2* r2 = (float2*)(ws + 0x1640000);                         // 64 KB
  _Float16* ey16 = (_Float16*)(ws + 0x1650000);                   // 16 KB
  _Float16* ez16 = (_Float16*)(ws + 0x1654000);                   // 16 KB
  float* s2x = (float*)(ws + 0x1658000);                          // 32 KB
  float* corr = (float*)(ws + 0x1660000);                         // 512 B
  float* part = (float*)(ws + 0x1700000);                         // 16 MB [k4..k5]

  k1_wh<<<NN / 32, 256, 0, stream>>>(h, W, b, a, Wh, r4, c4, r2, ey16, ez16, s2x, corr);
  k2_stats<<<512, 256, 0, stream>>>(adj, r4, s2x, bits, zpart);
  k3_scale<<<NN / 64, 256, 0, stream>>>(Wh, c4, zpart, Wfrag, corr);
  k4_main<<<1024, 256, 0, stream>>>(bits, r2, ey16, ez16, Wfrag, part);
  k5_fin<<<(NN * FO / 4) / 256, 256, 0, stream>>>(part, corr, out);
}